// Round 1
// baseline (411.506 us; speedup 1.0000x reference)
//
#include <hip/hip_runtime.h>

// Problem constants (B,C,S,E) = (8,16,512,256), fp32 in/out.
constexpr int BATCH = 8;
constexpr int CYC   = 16;
constexpr int SEQ   = 512;
constexpr int EMB   = 256;

typedef __attribute__((ext_vector_type(8))) short bf16x8;
typedef __attribute__((ext_vector_type(4))) float f32x4;

__device__ __forceinline__ unsigned short f2bf(float x) {
    unsigned int u = __float_as_uint(x);
    u += 0x7fffu + ((u >> 16) & 1u);   // RNE
    return (unsigned short)(u >> 16);
}
__device__ __forceinline__ unsigned int pk2(float lo, float hi) {
    return (unsigned int)f2bf(lo) | ((unsigned int)f2bf(hi) << 16);
}
__device__ __forceinline__ f32x4 mfma16(bf16x8 a, bf16x8 b, f32x4 c) {
    return __builtin_amdgcn_mfma_f32_16x16x32_bf16(a, b, c, 0, 0, 0);
}
// async global->LDS, 16B/lane; LDS dst = wave-uniform base + lane*16
__device__ __forceinline__ void gll16(const void* g, void* l) {
    __builtin_amdgcn_global_load_lds(
        (const __attribute__((address_space(1))) void*)g,
        (__attribute__((address_space(3))) void*)l, 16, 0, 0);
}
union BCast { int4 i; bf16x8 v; };

// ---------------------------------------------------------------------------
// Kernel 0: W[c][e][f] fp32 -> Wt[c][f][e] bf16.  grid (4,4,3*C), block 256.
// z>>4 selects q/k/v, z&15 = c.
// ---------------------------------------------------------------------------
__global__ __launch_bounds__(256) void wt_kernel(
    const float* __restrict__ Wq, const float* __restrict__ Wk,
    const float* __restrict__ Wv,
    unsigned short* __restrict__ Tq, unsigned short* __restrict__ Tk,
    unsigned short* __restrict__ Tv)
{
    __shared__ float tile[64][65];
    const int z = blockIdx.z;
    const int which = z >> 4, c = z & 15;
    const float* W = which == 0 ? Wq : which == 1 ? Wk : Wv;
    unsigned short* Wt = which == 0 ? Tq : which == 1 ? Tk : Tv;
    const int e0 = blockIdx.x * 64;
    const int f0 = blockIdx.y * 64;
    const float* Wc = W + (size_t)c * EMB * EMB;
    unsigned short* Wtc = Wt + (size_t)c * EMB * EMB;
    const int t = threadIdx.x;
    {
        const int er = t >> 4;
        const int fc = (t & 15) * 4;
        for (int i = 0; i < 4; ++i) {
            const float4 v = *(const float4*)(Wc + (size_t)(e0 + er + i * 16) * EMB + f0 + fc);
            tile[er + i * 16][fc + 0] = v.x;
            tile[er + i * 16][fc + 1] = v.y;
            tile[er + i * 16][fc + 2] = v.z;
            tile[er + i * 16][fc + 3] = v.w;
        }
    }
    __syncthreads();
    {
        const int fr = t >> 4;
        const int ec = (t & 15) * 4;
        for (int i = 0; i < 4; ++i) {
            const int f = fr + i * 16;
            ushort4 o;
            o.x = f2bf(tile[ec + 0][f]);
            o.y = f2bf(tile[ec + 1][f]);
            o.z = f2bf(tile[ec + 2][f]);
            o.w = f2bf(tile[ec + 3][f]);
            *(ushort4*)(Wtc + (size_t)(f0 + f) * EMB + e0 + ec) = o;
        }
    }
}

// ---------------------------------------------------------------------------
// Kernel 1: merged q/k/v projection.  Y = relu(X_f32 @ W + bias) * scale.
// grid (128, 8, 3): x=bc (128%8==0 -> same c on same XCD for W L2 reuse),
// y=m-tile, z selects projection.  Tile 64(m) x 256(n=full E), K-step 32.
//
// Double-buffered LDS, ALL staging via global_load_lds (6 calls/wave/step),
// counted s_waitcnt vmcnt(6): the k+1 prefetch stays in flight across the
// barrier (T3/T4-min) instead of being drained by __syncthreads' vmcnt(0).
//   A: fp32 staged raw, source chunk-XOR-swizzled (chunk^row&7) so the
//      ds_read_b128 frag reads are bank-spread; pack fp32->bf16 on read.
//   B: bf16, 64B row chunks, XOR chunk swizzle (unchanged, verified).
// Two raw s_barriers per K-step:
//   B1: [issue gll k+1][vmcnt(6)][barrier]  -> tile k is ready for all waves
//   B2: [sched_barrier][lgkmcnt(0)][barrier] -> all frag reads of buf done
//       before anyone glls into it next iteration (m152-safe).
// ---------------------------------------------------------------------------
__global__ __launch_bounds__(256, 3) void proj_kernel(
    const float* __restrict__ Xq, const float* __restrict__ Xk,
    const float* __restrict__ Xv,
    const unsigned short* __restrict__ Wq, const unsigned short* __restrict__ Wk,
    const unsigned short* __restrict__ Wv,
    const float* __restrict__ Bq, const float* __restrict__ Bk,
    const float* __restrict__ Bv,
    unsigned short* __restrict__ Yq, unsigned short* __restrict__ Yk,
    unsigned short* __restrict__ Yv)
{
    __shared__ float          As[2][64 * 32];    // 16 KiB, raw fp32, chunk-swizzled
    __shared__ unsigned short Bs[2][256 * 32];   // 32 KiB, bf16, chunk-swizzled

    const int z = blockIdx.z;
    const float* X = z == 0 ? Xq : z == 1 ? Xk : Xv;
    const unsigned short* Wt = z == 0 ? Wq : z == 1 ? Wk : Wv;
    const float* bias = z == 0 ? Bq : z == 1 ? Bk : Bv;
    unsigned short* Y = z == 0 ? Yq : z == 1 ? Yk : Yv;
    const float scale = z == 0 ? 0.0625f : 1.0f;   // E^-0.5 folded into q

    const int bc = blockIdx.x;
    const int c  = bc & (CYC - 1);
    const int m0 = blockIdx.y * 64;
    const float* Xb = X + (size_t)bc * SEQ * EMB;
    const unsigned short* Wc = Wt + (size_t)c * EMB * EMB;
    const float* bb = bias + (size_t)c * EMB;
    unsigned short* Yb = Y + (size_t)bc * SEQ * EMB;

    const int tid  = threadIdx.x;
    const int lane = tid & 63, w = tid >> 6;
    const int ln   = lane & 15, quad = lane >> 4;
    const int wu   = __builtin_amdgcn_readfirstlane(w);

    // A gll: per call 8 rows x 128B; lane -> (row=lane>>3, chunk=lane&7),
    // source chunk pre-swizzled so LDS[r][c] = global chunk c^(r&7).
    const int arow = lane >> 3;
    const int achk = (lane & 7) ^ arow;
    // B gll: per call 16 rows x 64B; source chunk ^ ((row-in-group)>>1 & 3).
    const int brow = lane >> 2;
    const int gch  = (lane & 3) ^ ((lane >> 3) & 3);
    // frag-read constants
    const int s8    = ln & 7;                  // A un-swizzle
    const int bslot = quad ^ ((ln >> 1) & 3);  // B un-swizzle

    f32x4 acc[4][4];
    for (int i = 0; i < 4; ++i)
        for (int j = 0; j < 4; ++j) acc[i][j] = (f32x4){0.f, 0.f, 0.f, 0.f};

    auto stage = [&](int kk, int b) {
        const int k0 = kk * 32;
#pragma unroll
        for (int j = 0; j < 2; ++j) {          // A: 2 calls/wave
            const int r0 = wu * 16 + j * 8;
            gll16(Xb + (size_t)(m0 + r0 + arow) * EMB + k0 + achk * 4,
                  &As[b][r0 * 32]);
        }
#pragma unroll
        for (int j = 0; j < 4; ++j) {          // B: 4 calls/wave
            const int r0 = wu * 64 + j * 16;
            gll16(Wc + (size_t)(r0 + brow) * EMB + k0 + gch * 8,
                  &Bs[b][r0 * 32]);
        }
    };

    stage(0, 0);
#pragma unroll
    for (int kk = 0; kk < 8; ++kk) {
        const int cur = kk & 1;
        if (kk < 7) {
            stage(kk + 1, cur ^ 1);
            asm volatile("s_waitcnt vmcnt(6)" ::: "memory");   // tile kk done
        } else {
            asm volatile("s_waitcnt vmcnt(0)" ::: "memory");
        }
        __builtin_amdgcn_s_barrier();
        __builtin_amdgcn_sched_barrier(0);

        bf16x8 af[4], bfv[4];
#pragma unroll
        for (int i = 0; i < 4; ++i) {          // A frag: 2x b128 fp32 + pack
            const float* ar = &As[cur][(i * 16 + ln) * 32];
            const float4 f0 = *(const float4*)(ar + ((2 * quad)     ^ s8) * 4);
            const float4 f1 = *(const float4*)(ar + ((2 * quad + 1) ^ s8) * 4);
            BCast u;
            u.i.x = pk2(f0.x, f0.y); u.i.y = pk2(f0.z, f0.w);
            u.i.z = pk2(f1.x, f1.y); u.i.w = pk2(f1.z, f1.w);
            af[i] = u.v;
        }
#pragma unroll
        for (int j = 0; j < 4; ++j)
            bfv[j] = *(const bf16x8*)&Bs[cur][(w * 64 + j * 16 + ln) * 32 + bslot * 8];
#pragma unroll
        for (int i = 0; i < 4; ++i)
#pragma unroll
            for (int j = 0; j < 4; ++j)
                acc[i][j] = mfma16(af[i], bfv[j], acc[i][j]);

        __builtin_amdgcn_sched_barrier(0);
        asm volatile("s_waitcnt lgkmcnt(0)" ::: "memory");
        __builtin_amdgcn_s_barrier();
    }

    // Epilogue.  C/D layout: col = lane&15, row = quad*4 + reg  [m89-verified]
    float bvj[4];
#pragma unroll
    for (int j = 0; j < 4; ++j) bvj[j] = bb[w * 64 + j * 16 + ln];

    if (z != 2) {
        // per-wave LDS transpose tile [16][72] -> coalesced 16B row stores
        unsigned short* ep = (unsigned short*)&As[0][0] + w * 1152;
        for (int i = 0; i < 4; ++i) {
            for (int j = 0; j < 4; ++j)
                for (int r = 0; r < 4; ++r)
                    ep[(quad * 4 + r) * 72 + j * 16 + ln] =
                        f2bf(fmaxf(acc[i][j][r] + bvj[j], 0.f) * scale);
            __syncthreads();
            for (int h = 0; h < 2; ++h) {
                const int cid = lane + h * 64;       // [16 rows][8 chunks]
                const int row = cid >> 3, ch = cid & 7;
                *(bf16x8*)&Yb[(size_t)(m0 + i * 16 + row) * EMB + w * 64 + ch * 8] =
                    *(const bf16x8*)&ep[row * 72 + ch * 8];
            }
            __syncthreads();
        }
    } else {
        // V path: store transposed  Yb[f][t]
        for (int j = 0; j < 4; ++j) {
            const int fg = w * 64 + j * 16 + ln;
            for (int i = 0; i < 4; ++i) {
                const int mb = m0 + i * 16 + quad * 4;
                ushort4 u;
                u.x = f2bf(fmaxf(acc[i][j][0] + bvj[j], 0.f) * scale);
                u.y = f2bf(fmaxf(acc[i][j][1] + bvj[j], 0.f) * scale);
                u.z = f2bf(fmaxf(acc[i][j][2] + bvj[j], 0.f) * scale);
                u.w = f2bf(fmaxf(acc[i][j][3] + bvj[j], 0.f) * scale);
                *(ushort4*)&Yb[(size_t)fg * SEQ + mb] = u;
            }
        }
    }
}

// ---------------------------------------------------------------------------
// Kernel 2: attention per (b,c).  grid (128, 8).
// No max-subtraction (q,k are relu outputs -> scores >= 0, exp safe in fp32).
// v2: K read DIRECTLY from global in QK^T (32x256 chunk is L1/L2-resident,
//     shared by the 4 waves) -> K staging + one barrier removed.
//     V double-buffered in LDS via gll + counted vmcnt(4) so the prefetch
//     survives the barrier.  2 barriers/tt instead of 3, LDS 42.5->37 KB.
// ---------------------------------------------------------------------------
__global__ __launch_bounds__(256, 3) void attn_kernel(
    const unsigned short* __restrict__ Qp, const unsigned short* __restrict__ Kp,
    const unsigned short* __restrict__ Vt, float* __restrict__ Out)
{
    __shared__ unsigned short Vs[2][256 * 32];  // [e][t-chunk], chunk-swizzled
    __shared__ unsigned short Ps[64][40];       // [m][t]
    const int bc = blockIdx.x;
    const int qt = blockIdx.y;
    const unsigned short* Qb = Qp + (size_t)bc * SEQ * EMB;
    const unsigned short* Kb = Kp + (size_t)bc * SEQ * EMB;
    const unsigned short* Vb = Vt + (size_t)bc * SEQ * EMB;  // [e][t]
    float* Ob = Out + (size_t)bc * SEQ * EMB;

    const int tid  = threadIdx.x;
    const int lane = tid & 63, w = tid >> 6;
    const int ln   = lane & 15, quad = lane >> 4;
    const int wu   = __builtin_amdgcn_readfirstlane(w);
    const int brow = lane >> 2;
    const int gch  = (lane & 3) ^ ((lane >> 3) & 3);
    const int vslot = quad ^ ((ln >> 1) & 3);

    bf16x8 qf[8];
    const int qrow = qt * 64 + w * 16 + ln;
#pragma unroll
    for (int ke = 0; ke < 8; ++ke)
        qf[ke] = *(const bf16x8*)(Qb + (size_t)qrow * EMB + ke * 32 + quad * 8);

    f32x4 of[16];
    for (int n = 0; n < 16; ++n) of[n] = (f32x4){0.f, 0.f, 0.f, 0.f};
    float lsum[4] = {0.f, 0.f, 0.f, 0.f};

    auto stageV = [&](int tt, int b) {
        const int t0 = tt * 32;
#pragma unroll
        for (int j = 0; j < 4; ++j) {           // 4 calls/wave, 16 rows x 64B
            const int r0 = wu * 64 + j * 16;
            gll16(Vb + (size_t)(r0 + brow) * SEQ + t0 + gch * 8,
                  &Vs[b][r0 * 32]);
        }
    };

    stageV(0, 0);

    const unsigned short* Kq = Kb + (size_t)ln * EMB + quad * 8;

    for (int tt = 0; tt < 16; ++tt) {
        const int cur = tt & 1;
        const int t0 = tt * 32;

        // QK^T straight from global (L1 shares the chunk across the 4 waves)
        f32x4 sf0 = (f32x4){0.f,0.f,0.f,0.f}, sf1 = (f32x4){0.f,0.f,0.f,0.f};
        const unsigned short* K0 = Kq + (size_t)t0 * EMB;
#pragma unroll
        for (int ke = 0; ke < 8; ++ke) {
            bf16x8 b0 = *(const bf16x8*)(K0 + ke * 32);
            bf16x8 b1 = *(const bf16x8*)(K0 + (size_t)16 * EMB + ke * 32);
            sf0 = mfma16(qf[ke], b0, sf0);
            sf1 = mfma16(qf[ke], b1, sf1);
        }

        float p0[4], p1[4];
#pragma unroll
        for (int r = 0; r < 4; ++r) {
            p0[r] = __expf(sf0[r]);
            p1[r] = __expf(sf1[r]);
            lsum[r] += p0[r] + p1[r];
        }
#pragma unroll
        for (int r = 0; r < 4; ++r) {
            Ps[w * 16 + quad * 4 + r][ln]      = f2bf(p0[r]);
            Ps[w * 16 + quad * 4 + r][16 + ln] = f2bf(p1[r]);
        }

        // prefetch V(tt+1) into the other buffer; wait only for V(tt)
        if (tt < 15) {
            stageV(tt + 1, cur ^ 1);
            asm volatile("s_waitcnt vmcnt(4) lgkmcnt(0)" ::: "memory");
        } else {
            asm volatile("s_waitcnt vmcnt(0) lgkmcnt(0)" ::: "memory");
        }
        __builtin_amdgcn_s_barrier();
        __builtin_amdgcn_sched_barrier(0);

        // PV: O[m][e] += P[m][t] V[t][e]
        bf16x8 af = *(const bf16x8*)&Ps[w * 16 + ln][quad * 8];
#pragma unroll
        for (int n = 0; n < 16; ++n) {
            bf16x8 bv = *(const bf16x8*)&Vs[cur][(n * 16 + ln) * 32 + vslot * 8];
            of[n] = mfma16(af, bv, of[n]);
        }
        __builtin_amdgcn_sched_barrier(0);
        asm volatile("s_waitcnt lgkmcnt(0)" ::: "memory");
        __builtin_amdgcn_s_barrier();
    }

    for (int off = 1; off < 16; off <<= 1)
        for (int r = 0; r < 4; ++r)
            lsum[r] += __shfl_xor(lsum[r], off, 64);
    float inv[4];
    for (int r = 0; r < 4; ++r) inv[r] = 1.0f / lsum[r];
    const int mbase = qt * 64 + w * 16 + quad * 4;
    for (int n = 0; n < 16; ++n)
        for (int r = 0; r < 4; ++r)
            Ob[(size_t)(mbase + r) * EMB + n * 16 + ln] = of[n][r] * inv[r];
}

// ---------------------------------------------------------------------------
extern "C" void kernel_launch(void* const* d_in, const int* in_sizes, int n_in,
                              void* d_out, int out_size, void* d_ws, size_t ws_size,
                              hipStream_t stream) {
    const float* query = (const float*)d_in[0];
    const float* key_  = (const float*)d_in[1];
    const float* value = (const float*)d_in[2];
    const float* wq = (const float*)d_in[3];
    const float* wk = (const float*)d_in[4];
    const float* wv = (const float*)d_in[5];
    const float* bq = (const float*)d_in[6];
    const float* bk = (const float*)d_in[7];
    const float* bv = (const float*)d_in[8];
    float* out = (float*)d_out;

    // Workspace: Wt q/k/v bf16 (2 MiB ea) | Qp, Kp, Vtp bf16 (32 MiB ea)
    char* ws = (char*)d_ws;
    const size_t wsz = (size_t)CYC * EMB * EMB * sizeof(unsigned short);
    const size_t psz = (size_t)BATCH * CYC * SEQ * EMB * sizeof(unsigned short);
    unsigned short* Wtq = (unsigned short*)(ws);
    unsigned short* Wtk = (unsigned short*)(ws + wsz);
    unsigned short* Wtv = (unsigned short*)(ws + 2 * wsz);
    unsigned short* Qp  = (unsigned short*)(ws + 3 * wsz);
    unsigned short* Kp  = (unsigned short*)(ws + 3 * wsz + psz);
    unsigned short* Vtp = (unsigned short*)(ws + 3 * wsz + 2 * psz);

    const dim3 tb(256);
    wt_kernel<<<dim3(4, 4, 3 * CYC), tb, 0, stream>>>(wq, wk, wv, Wtq, Wtk, Wtv);

    proj_kernel<<<dim3(BATCH * CYC, SEQ / 64, 3), tb, 0, stream>>>(
        query, key_, value, Wtq, Wtk, Wtv, bq, bk, bv, Qp, Kp, Vtp);

    attn_kernel<<<dim3(BATCH * CYC, SEQ / 64), tb, 0, stream>>>(Qp, Kp, Vtp, out);
}

// Round 2
// 334.958 us; speedup vs baseline: 1.2285x; 1.2285x over previous
//
#include <hip/hip_runtime.h>

// Problem constants (B,C,S,E) = (8,16,512,256), fp32 in/out.
constexpr int BATCH = 8;
constexpr int CYC   = 16;
constexpr int SEQ   = 512;
constexpr int EMB   = 256;

typedef __attribute__((ext_vector_type(8))) short bf16x8;
typedef __attribute__((ext_vector_type(4))) float f32x4;

__device__ __forceinline__ unsigned short f2bf(float x) {
    unsigned int u = __float_as_uint(x);
    u += 0x7fffu + ((u >> 16) & 1u);   // RNE
    return (unsigned short)(u >> 16);
}
__device__ __forceinline__ unsigned int pk2(float lo, float hi) {
    return (unsigned int)f2bf(lo) | ((unsigned int)f2bf(hi) << 16);
}
__device__ __forceinline__ f32x4 mfma16(bf16x8 a, bf16x8 b, f32x4 c) {
    return __builtin_amdgcn_mfma_f32_16x16x32_bf16(a, b, c, 0, 0, 0);
}
// async global->LDS, 16B/lane; LDS dst = wave-uniform base + lane*16
__device__ __forceinline__ void gll16(const void* g, void* l) {
    __builtin_amdgcn_global_load_lds(
        (const __attribute__((address_space(1))) void*)g,
        (__attribute__((address_space(3))) void*)l, 16, 0, 0);
}
union BCast { int4 i; bf16x8 v; };

// ---------------------------------------------------------------------------
// Kernel 0: W[c][e][f] fp32 -> Wt[c][f][e] bf16.  grid (4,4,3*C), block 256.
// z>>4 selects q/k/v, z&15 = c.
// ---------------------------------------------------------------------------
__global__ __launch_bounds__(256) void wt_kernel(
    const float* __restrict__ Wq, const float* __restrict__ Wk,
    const float* __restrict__ Wv,
    unsigned short* __restrict__ Tq, unsigned short* __restrict__ Tk,
    unsigned short* __restrict__ Tv)
{
    __shared__ float tile[64][65];
    const int z = blockIdx.z;
    const int which = z >> 4, c = z & 15;
    const float* W = which == 0 ? Wq : which == 1 ? Wk : Wv;
    unsigned short* Wt = which == 0 ? Tq : which == 1 ? Tk : Tv;
    const int e0 = blockIdx.x * 64;
    const int f0 = blockIdx.y * 64;
    const float* Wc = W + (size_t)c * EMB * EMB;
    unsigned short* Wtc = Wt + (size_t)c * EMB * EMB;
    const int t = threadIdx.x;
    {
        const int er = t >> 4;
        const int fc = (t & 15) * 4;
        for (int i = 0; i < 4; ++i) {
            const float4 v = *(const float4*)(Wc + (size_t)(e0 + er + i * 16) * EMB + f0 + fc);
            tile[er + i * 16][fc + 0] = v.x;
            tile[er + i * 16][fc + 1] = v.y;
            tile[er + i * 16][fc + 2] = v.z;
            tile[er + i * 16][fc + 3] = v.w;
        }
    }
    __syncthreads();
    {
        const int fr = t >> 4;
        const int ec = (t & 15) * 4;
        for (int i = 0; i < 4; ++i) {
            const int f = fr + i * 16;
            ushort4 o;
            o.x = f2bf(tile[ec + 0][f]);
            o.y = f2bf(tile[ec + 1][f]);
            o.z = f2bf(tile[ec + 2][f]);
            o.w = f2bf(tile[ec + 3][f]);
            *(ushort4*)(Wtc + (size_t)(f0 + f) * EMB + e0 + ec) = o;
        }
    }
}

// ---------------------------------------------------------------------------
// Kernel 1: merged q/k/v projection.  Y = relu(X_f32 @ W + bias) * scale.
// grid (128, 8, 3): x=bc (128%8==0 -> same c on same XCD for W L2 reuse),
// y=m-tile, z selects projection.  Tile 64(m) x 256(n=full E), K-step 32.
// UNCHANGED from round 1 (isolated A/B: only attn changes this round).
// ---------------------------------------------------------------------------
__global__ __launch_bounds__(256, 3) void proj_kernel(
    const float* __restrict__ Xq, const float* __restrict__ Xk,
    const float* __restrict__ Xv,
    const unsigned short* __restrict__ Wq, const unsigned short* __restrict__ Wk,
    const unsigned short* __restrict__ Wv,
    const float* __restrict__ Bq, const float* __restrict__ Bk,
    const float* __restrict__ Bv,
    unsigned short* __restrict__ Yq, unsigned short* __restrict__ Yk,
    unsigned short* __restrict__ Yv)
{
    __shared__ float          As[2][64 * 32];    // 16 KiB, raw fp32, chunk-swizzled
    __shared__ unsigned short Bs[2][256 * 32];   // 32 KiB, bf16, chunk-swizzled

    const int z = blockIdx.z;
    const float* X = z == 0 ? Xq : z == 1 ? Xk : Xv;
    const unsigned short* Wt = z == 0 ? Wq : z == 1 ? Wk : Wv;
    const float* bias = z == 0 ? Bq : z == 1 ? Bk : Bv;
    unsigned short* Y = z == 0 ? Yq : z == 1 ? Yk : Yv;
    const float scale = z == 0 ? 0.0625f : 1.0f;   // E^-0.5 folded into q

    const int bc = blockIdx.x;
    const int c  = bc & (CYC - 1);
    const int m0 = blockIdx.y * 64;
    const float* Xb = X + (size_t)bc * SEQ * EMB;
    const unsigned short* Wc = Wt + (size_t)c * EMB * EMB;
    const float* bb = bias + (size_t)c * EMB;
    unsigned short* Yb = Y + (size_t)bc * SEQ * EMB;

    const int tid  = threadIdx.x;
    const int lane = tid & 63, w = tid >> 6;
    const int ln   = lane & 15, quad = lane >> 4;
    const int wu   = __builtin_amdgcn_readfirstlane(w);

    // A gll: per call 8 rows x 128B; lane -> (row=lane>>3, chunk=lane&7),
    // source chunk pre-swizzled so LDS[r][c] = global chunk c^(r&7).
    const int arow = lane >> 3;
    const int achk = (lane & 7) ^ arow;
    // B gll: per call 16 rows x 64B; source chunk ^ ((row-in-group)>>1 & 3).
    const int brow = lane >> 2;
    const int gch  = (lane & 3) ^ ((lane >> 3) & 3);
    // frag-read constants
    const int s8    = ln & 7;                  // A un-swizzle
    const int bslot = quad ^ ((ln >> 1) & 3);  // B un-swizzle

    f32x4 acc[4][4];
    for (int i = 0; i < 4; ++i)
        for (int j = 0; j < 4; ++j) acc[i][j] = (f32x4){0.f, 0.f, 0.f, 0.f};

    auto stage = [&](int kk, int b) {
        const int k0 = kk * 32;
#pragma unroll
        for (int j = 0; j < 2; ++j) {          // A: 2 calls/wave
            const int r0 = wu * 16 + j * 8;
            gll16(Xb + (size_t)(m0 + r0 + arow) * EMB + k0 + achk * 4,
                  &As[b][r0 * 32]);
        }
#pragma unroll
        for (int j = 0; j < 4; ++j) {          // B: 4 calls/wave
            const int r0 = wu * 64 + j * 16;
            gll16(Wc + (size_t)(r0 + brow) * EMB + k0 + gch * 8,
                  &Bs[b][r0 * 32]);
        }
    };

    stage(0, 0);
#pragma unroll
    for (int kk = 0; kk < 8; ++kk) {
        const int cur = kk & 1;
        if (kk < 7) {
            stage(kk + 1, cur ^ 1);
            asm volatile("s_waitcnt vmcnt(6)" ::: "memory");   // tile kk done
        } else {
            asm volatile("s_waitcnt vmcnt(0)" ::: "memory");
        }
        __builtin_amdgcn_s_barrier();
        __builtin_amdgcn_sched_barrier(0);

        bf16x8 af[4], bfv[4];
#pragma unroll
        for (int i = 0; i < 4; ++i) {          // A frag: 2x b128 fp32 + pack
            const float* ar = &As[cur][(i * 16 + ln) * 32];
            const float4 f0 = *(const float4*)(ar + ((2 * quad)     ^ s8) * 4);
            const float4 f1 = *(const float4*)(ar + ((2 * quad + 1) ^ s8) * 4);
            BCast u;
            u.i.x = pk2(f0.x, f0.y); u.i.y = pk2(f0.z, f0.w);
            u.i.z = pk2(f1.x, f1.y); u.i.w = pk2(f1.z, f1.w);
            af[i] = u.v;
        }
#pragma unroll
        for (int j = 0; j < 4; ++j)
            bfv[j] = *(const bf16x8*)&Bs[cur][(w * 64 + j * 16 + ln) * 32 + bslot * 8];
#pragma unroll
        for (int i = 0; i < 4; ++i)
#pragma unroll
            for (int j = 0; j < 4; ++j)
                acc[i][j] = mfma16(af[i], bfv[j], acc[i][j]);

        __builtin_amdgcn_sched_barrier(0);
        asm volatile("s_waitcnt lgkmcnt(0)" ::: "memory");
        __builtin_amdgcn_s_barrier();
    }

    // Epilogue.  C/D layout: col = lane&15, row = quad*4 + reg  [m89-verified]
    float bvj[4];
#pragma unroll
    for (int j = 0; j < 4; ++j) bvj[j] = bb[w * 64 + j * 16 + ln];

    if (z != 2) {
        // per-wave LDS transpose tile [16][72] -> coalesced 16B row stores
        unsigned short* ep = (unsigned short*)&As[0][0] + w * 1152;
        for (int i = 0; i < 4; ++i) {
            for (int j = 0; j < 4; ++j)
                for (int r = 0; r < 4; ++r)
                    ep[(quad * 4 + r) * 72 + j * 16 + ln] =
                        f2bf(fmaxf(acc[i][j][r] + bvj[j], 0.f) * scale);
            __syncthreads();
            for (int h = 0; h < 2; ++h) {
                const int cid = lane + h * 64;       // [16 rows][8 chunks]
                const int row = cid >> 3, ch = cid & 7;
                *(bf16x8*)&Yb[(size_t)(m0 + i * 16 + row) * EMB + w * 64 + ch * 8] =
                    *(const bf16x8*)&ep[row * 72 + ch * 8];
            }
            __syncthreads();
        }
    } else {
        // V path: store transposed  Yb[f][t]
        for (int j = 0; j < 4; ++j) {
            const int fg = w * 64 + j * 16 + ln;
            for (int i = 0; i < 4; ++i) {
                const int mb = m0 + i * 16 + quad * 4;
                ushort4 u;
                u.x = f2bf(fmaxf(acc[i][j][0] + bvj[j], 0.f) * scale);
                u.y = f2bf(fmaxf(acc[i][j][1] + bvj[j], 0.f) * scale);
                u.z = f2bf(fmaxf(acc[i][j][2] + bvj[j], 0.f) * scale);
                u.w = f2bf(fmaxf(acc[i][j][3] + bvj[j], 0.f) * scale);
                *(ushort4*)&Yb[(size_t)fg * SEQ + mb] = u;
            }
        }
    }
}

// ---------------------------------------------------------------------------
// Kernel 2: attention per (b,c) — round-0 structure (85 us verified) + T14:
// K/V tile tt+1 global->reg loads issued right after the staging barrier, so
// their HBM/L2 latency flies under QK^T + softmax + PV (~500+ cycles of
// compute); regs are written to LDS at the top of the next iteration.
// No max-subtraction (q,k are relu outputs -> scores >= 0, exp safe in fp32).
// grid (128, 8): x=bc (same-XCD L2 reuse of K/V across the 8 qt blocks).
// ---------------------------------------------------------------------------
__global__ __launch_bounds__(256) void attn_kernel(
    const unsigned short* __restrict__ Qp, const unsigned short* __restrict__ Kp,
    const unsigned short* __restrict__ Vt, float* __restrict__ Out)
{
    __shared__ unsigned short Ks[32][264];  // [t][e]
    __shared__ unsigned short Vs[256][40];  // [e][t]
    __shared__ unsigned short Ps[64][40];   // [m][t]
    const int bc = blockIdx.x;
    const int qt = blockIdx.y;
    const unsigned short* Qb = Qp + (size_t)bc * SEQ * EMB;
    const unsigned short* Kb = Kp + (size_t)bc * SEQ * EMB;
    const unsigned short* Vb = Vt + (size_t)bc * SEQ * EMB;  // [e][t]
    float* Ob = Out + (size_t)bc * SEQ * EMB;

    const int tid  = threadIdx.x;
    const int lane = tid & 63, w = tid >> 6;
    const int ln   = lane & 15, quad = lane >> 4;

    bf16x8 qf[8];
    const int qrow = qt * 64 + w * 16 + ln;
#pragma unroll
    for (int ke = 0; ke < 8; ++ke)
        qf[ke] = *(const bf16x8*)(Qb + (size_t)qrow * EMB + ke * 32 + quad * 8);

    f32x4 of[16];
    for (int n = 0; n < 16; ++n) of[n] = (f32x4){0.f, 0.f, 0.f, 0.f};
    float lsum[4] = {0.f, 0.f, 0.f, 0.f};

    // T14 register staging (32 VGPRs): same addressing as the LDS writes.
    bf16x8 kreg[4], vreg[4];
    auto loadKV = [&](int tt) {
        const int t0 = tt * 32;
#pragma unroll
        for (int i = 0; i < 4; ++i) {       // K chunk: 32 x 256 bf16
            const int idx = tid + i * 256;
            const int r = idx >> 5, c8 = (idx & 31) * 8;
            kreg[i] = *(const bf16x8*)(Kb + (size_t)(t0 + r) * EMB + c8);
        }
#pragma unroll
        for (int i = 0; i < 4; ++i) {       // V chunk: 256 x 32 bf16
            const int idx = tid + i * 256;
            const int e = idx >> 2, c8 = (idx & 3) * 8;
            vreg[i] = *(const bf16x8*)(Vb + (size_t)e * SEQ + t0 + c8);
        }
    };
    loadKV(0);

    for (int tt = 0; tt < 16; ++tt) {
        // write staged regs -> LDS (previous iteration's final barrier
        // guarantees Ks/Vs are no longer being read)
#pragma unroll
        for (int i = 0; i < 4; ++i) {
            const int idx = tid + i * 256;
            const int r = idx >> 5, c8 = (idx & 31) * 8;
            *(bf16x8*)&Ks[r][c8] = kreg[i];
        }
#pragma unroll
        for (int i = 0; i < 4; ++i) {
            const int idx = tid + i * 256;
            const int e = idx >> 2, c8 = (idx & 3) * 8;
            *(bf16x8*)&Vs[e][c8] = vreg[i];
        }
        __syncthreads();
        if (tt < 15) loadKV(tt + 1);        // latency hides under QK + PV

        // QK^T
        f32x4 sf0 = (f32x4){0.f,0.f,0.f,0.f}, sf1 = (f32x4){0.f,0.f,0.f,0.f};
#pragma unroll
        for (int ke = 0; ke < 8; ++ke) {
            bf16x8 b0 = *(const bf16x8*)&Ks[ln][ke * 32 + quad * 8];
            bf16x8 b1 = *(const bf16x8*)&Ks[16 + ln][ke * 32 + quad * 8];
            sf0 = mfma16(qf[ke], b0, sf0);
            sf1 = mfma16(qf[ke], b1, sf1);
        }

        float p0[4], p1[4];
#pragma unroll
        for (int r = 0; r < 4; ++r) {
            p0[r] = __expf(sf0[r]);
            p1[r] = __expf(sf1[r]);
            lsum[r] += p0[r] + p1[r];
        }
#pragma unroll
        for (int r = 0; r < 4; ++r) {
            Ps[w * 16 + quad * 4 + r][ln]      = f2bf(p0[r]);
            Ps[w * 16 + quad * 4 + r][16 + ln] = f2bf(p1[r]);
        }
        __syncthreads();

        // PV: O[m][e] += P[m][t] V[t][e]
        bf16x8 af = *(const bf16x8*)&Ps[w * 16 + ln][quad * 8];
#pragma unroll
        for (int n = 0; n < 16; ++n) {
            bf16x8 bv = *(const bf16x8*)&Vs[n * 16 + ln][quad * 8];
            of[n] = mfma16(af, bv, of[n]);
        }
        __syncthreads();
    }

    for (int off = 1; off < 16; off <<= 1)
        for (int r = 0; r < 4; ++r)
            lsum[r] += __shfl_xor(lsum[r], off, 64);
    float inv[4];
    for (int r = 0; r < 4; ++r) inv[r] = 1.0f / lsum[r];
    const int mbase = qt * 64 + w * 16 + quad * 4;
    for (int n = 0; n < 16; ++n)
        for (int r = 0; r < 4; ++r)
            Ob[(size_t)(mbase + r) * EMB + n * 16 + ln] = of[n][r] * inv[r];
}

// ---------------------------------------------------------------------------
extern "C" void kernel_launch(void* const* d_in, const int* in_sizes, int n_in,
                              void* d_out, int out_size, void* d_ws, size_t ws_size,
                              hipStream_t stream) {
    const float* query = (const float*)d_in[0];
    const float* key_  = (const float*)d_in[1];
    const float* value = (const float*)d_in[2];
    const float* wq = (const float*)d_in[3];
    const float* wk = (const float*)d_in[4];
    const float* wv = (const float*)d_in[5];
    const float* bq = (const float*)d_in[6];
    const float* bk = (const float*)d_in[7];
    const float* bv = (const float*)d_in[8];
    float* out = (float*)d_out;

    // Workspace: Wt q/k/v bf16 (2 MiB ea) | Qp, Kp, Vtp bf16 (32 MiB ea)
    char* ws = (char*)d_ws;
    const size_t wsz = (size_t)CYC * EMB * EMB * sizeof(unsigned short);
    const size_t psz = (size_t)BATCH * CYC * SEQ * EMB * sizeof(unsigned short);
    unsigned short* Wtq = (unsigned short*)(ws);
    unsigned short* Wtk = (unsigned short*)(ws + wsz);
    unsigned short* Wtv = (unsigned short*)(ws + 2 * wsz);
    unsigned short* Qp  = (unsigned short*)(ws + 3 * wsz);
    unsigned short* Kp  = (unsigned short*)(ws + 3 * wsz + psz);
    unsigned short* Vtp = (unsigned short*)(ws + 3 * wsz + 2 * psz);

    const dim3 tb(256);
    wt_kernel<<<dim3(4, 4, 3 * CYC), tb, 0, stream>>>(wq, wk, wv, Wtq, Wtk, Wtv);

    proj_kernel<<<dim3(BATCH * CYC, SEQ / 64, 3), tb, 0, stream>>>(
        query, key_, value, Wtq, Wtk, Wtv, bq, bk, bv, Qp, Kp, Vtp);

    attn_kernel<<<dim3(BATCH * CYC, SEQ / 64), tb, 0, stream>>>(Qp, Kp, Vtp, out);
}